// Round 3
// baseline (271.345 us; speedup 1.0000x reference)
//
#include <hip/hip_runtime.h>
#include <hip/hip_bf16.h>

#define B_  8
#define S_  2048
#define H_  6
#define DK_ 24
#define DM_ 144

// tanh(SCALE*c) ~= c*(K0 + K1*t + K2*t^2), t = c^2, SCALE = 0.1/sqrt(24).
#define TK0  2.0412414523193153e-02f
#define TK1 -2.8350575726379381e-06f
#define TK2  4.7250959543965635e-10f

typedef __bf16 bf16x8 __attribute__((ext_vector_type(8)));
typedef __bf16 bf16x2 __attribute__((ext_vector_type(2)));
typedef float  f32x4  __attribute__((ext_vector_type(4)));
typedef float  f32x2  __attribute__((ext_vector_type(2)));

#define MFMA_ __builtin_amdgcn_mfma_f32_16x16x32_bf16

__device__ __forceinline__ unsigned short f2bf(float f) {
    return __builtin_bit_cast(unsigned short, (__bf16)f);
}
__device__ __forceinline__ uint pack2(float a, float b) {
    bf16x2 v; v[0] = (__bf16)a; v[1] = (__bf16)b;
    return __builtin_bit_cast(uint, v);
}
// packed tanh on a pair -> packed bf16 word (v_pk_mul_f32 / v_pk_fma_f32).
__device__ __forceinline__ uint tanh2_pack(float a, float b) {
    f32x2 c; c[0] = a; c[1] = b;
    f32x2 t = c * c;
    f32x2 u = t * TK2 + TK1;
    u = t * u + TK0;
    f32x2 r = c * u;
    return pack2(r[0], r[1]);
}

// lane-bit-5 swap: x' <- lower-32-half data of {x,y}; y' <- upper-half data.
__device__ __forceinline__ void swap32(uint &x, uint &y) {
    auto r = __builtin_amdgcn_permlane32_swap(x, y, false, false);
    x = r[0]; y = r[1];
}
// lane-bit-4 swap: x' <- bit4==0 data of {x,y}; y' <- bit4==1 data.
__device__ __forceinline__ void swap16(uint &x, uint &y, bool hi16) {
#if __has_builtin(__builtin_amdgcn_permlane16_swap)
    (void)hi16;
    auto r = __builtin_amdgcn_permlane16_swap(x, y, false, false);
    x = r[0]; y = r[1];
#else
    uint xs = __builtin_amdgcn_ds_swizzle(x, 0x401F);   // lane ^ 16
    uint ys = __builtin_amdgcn_ds_swizzle(y, 0x401F);
    uint nx = hi16 ? ys : x;
    uint ny = hi16 ? y : xs;
    x = nx; y = ny;
#endif
}

// ---------------------------------------------------------------------------
// prep: fused weight prep + K/V retile (one dispatch).
// blocks 0..1535   : K f32 -> Ktt[bh][kt][64 s][32 dk] bf16 (cols 24..31 zero)
//                    V f32 -> Vtt[bh][kt][32 d][64 s] bf16 (rows 24..31 zero)
// blocks 1536..1745: Whq[6][32][160] bf16 (head-sliced Wq, bias at k=144) and
//                    Wlp[144][160] bf16 (lin_w, bias at k=144).
// ---------------------------------------------------------------------------
__global__ __launch_bounds__(256)
void prep_kernel(const float* __restrict__ K, const float* __restrict__ V,
                 const float* __restrict__ Wq, const float* __restrict__ Wqb,
                 const float* __restrict__ Wl, const float* __restrict__ lb,
                 ushort* __restrict__ Ktt, ushort* __restrict__ Vtt,
                 ushort* __restrict__ Whq, ushort* __restrict__ Wlp) {
    __shared__ float sv[64 * 25];
    const int t = threadIdx.x;
    const int bid = blockIdx.x;
    if (bid >= 1536) {                        // ---- weight part ----
        int i = (bid - 1536) * 256 + t;
        if (i < 30720) {                      // Whq: 6*32*160
            int h = i / 5120, rem = i % 5120;
            int d = rem / 160, c = rem % 160;
            float v = 0.f;
            if (d < DK_) {
                if (c < DM_)       v = Wq[(h * DK_ + d) * DM_ + c];
                else if (c == DM_) v = Wqb[h * DK_ + d];
            }
            Whq[i] = f2bf(v);
        } else if (i < 53760) {               // Wlp: 144*160
            int j = i - 30720;
            int r = j / 160, c = j % 160;
            float v = (c < DM_) ? Wl[r * DM_ + c] : (c == DM_ ? lb[r] : 0.f);
            Wlp[j] = f2bf(v);
        }
        return;
    }
    // ---- KV part ----
    const int kt = bid & 31, h = (bid >> 5) % H_, b = bid / (32 * H_);
    const int bh = b * H_ + h;
    const size_t tile = (size_t)(bh * 32 + kt);
    const float4* Ks = (const float4*)(K + ((size_t)bh * S_ + kt * 64) * DK_);
    ushort* Ko = Ktt + tile * 2048;
    for (int idx = t; idx < 384; idx += 256) {
        int r = idx / 6, c4 = (idx % 6) * 4;
        float4 v = Ks[idx];
        ushort4 u; u.x = f2bf(v.x); u.y = f2bf(v.y); u.z = f2bf(v.z); u.w = f2bf(v.w);
        *(ushort4*)&Ko[r * 32 + c4] = u;
    }
    if (t < 64) { uint4 z = {0u,0u,0u,0u}; *(uint4*)&Ko[t * 32 + 24] = z; }
    const float4* Vs = (const float4*)(V + ((size_t)bh * S_ + kt * 64) * DK_);
    for (int idx = t; idx < 384; idx += 256) {
        int r = idx / 6, c4 = (idx % 6) * 4;
        *(float4*)&sv[r * 25 + c4] = Vs[idx];
    }
    __syncthreads();
    int d = t >> 3, s8 = (t & 7) * 8;
    uint4 o = {0u,0u,0u,0u};
    if (d < DK_) {
        o.x = pack2(sv[(s8 + 0) * 25 + d], sv[(s8 + 1) * 25 + d]);
        o.y = pack2(sv[(s8 + 2) * 25 + d], sv[(s8 + 3) * 25 + d]);
        o.z = pack2(sv[(s8 + 4) * 25 + d], sv[(s8 + 5) * 25 + d]);
        o.w = pack2(sv[(s8 + 6) * 25 + d], sv[(s8 + 7) * 25 + d]);
    }
    ((uint4*)Vtt)[tile * 256 + t] = o;
}

// ---------------------------------------------------------------------------
// attn: fused qproj + tanh-attention.
// Block = 512 threads (8 waves) = 128 q-rows of one (b,h); wave owns 16 rows.
// Grid 768 = 3 blocks/CU, LDS 19.5KB, 24 waves/CU.
// K A-fragments load DIRECTLY from global Ktt (fragment layout == global
// layout; L1/L2-resident, VMEM pipe runs parallel to LDS pipe).
// V only in LDS (double-buffer, static phase addressing), staged by all 512
// threads (uint2 each); ONE barrier per k-tile.
// P never touches LDS: QK^T frag -> PV A-frag via permlane32/16 butterfly.
// Output: bf16 ctx tile into Cb[16384][160] (outln-staging layout).
// ---------------------------------------------------------------------------
__global__ __launch_bounds__(512, 6)
void attn_kernel(const float* __restrict__ Q, const ushort* __restrict__ Whq,
                 const ushort* __restrict__ Ktt, const ushort* __restrict__ Vtt,
                 ushort* __restrict__ Cb) {
    __shared__ __attribute__((aligned(16))) char smem[19456];
    ushort* s_q  = (ushort*)smem;             // 128 x pitch40    [0, 10240)
    ushort* s_vt = (ushort*)(smem + 10240);   // 2 x 32 x pitch72 [10240, 19456)
    float*  s_ctx = (float*)smem;             // epilogue alias: 128 x 28 f32

    const int t = threadIdx.x;
    const int w = t >> 6, n16 = t & 15, g = (t >> 4) & 3;
    const bool hi16 = (t & 16) != 0;
    const int qp = blockIdx.x, h = blockIdx.y, b = blockIdx.z;
    const int bh = b * H_ + h;
    const int row0 = qp * 128;

    const uint4* Kb4 = (const uint4*)Ktt + (size_t)bh * 8192;   // 32 tiles x 256
    const uint2* Vb2 = (const uint2*)Vtt + (size_t)bh * 16384;  // 32 tiles x 512

    // V staging: every thread stages one uint2 (8B). row = t>>4, col4 = t&15.
    const int stoff = (t >> 4) * 72 + (t & 15) * 4;
    uint2 vreg = Vb2[t];                      // preload tile 0

    // ---- Phase A: q = Q @ Whq^T + bias (k=144 col), frags from global ----
    const f32x4 zf = {0.f, 0.f, 0.f, 0.f};
    const uint4* Wh4 = (const uint4*)Whq + h * 640;
    {
        const float* Qr = Q + (size_t)(b * S_ + row0 + w * 16 + n16) * DM_;
        f32x4 qa0 = zf, qa1 = zf;
#pragma unroll
        for (int ks = 0; ks < 5; ++ks) {
            bf16x8 av;
            if (ks < 4 || g < 2) {            // real cols (ks=4,g<2 -> 128..143)
                float4 f0 = *(const float4*)&Qr[ks * 32 + g * 8];
                float4 f1 = *(const float4*)&Qr[ks * 32 + g * 8 + 4];
                uint4 u;
                u.x = pack2(f0.x, f0.y); u.y = pack2(f0.z, f0.w);
                u.z = pack2(f1.x, f1.y); u.w = pack2(f1.z, f1.w);
                av = __builtin_bit_cast(bf16x8, u);
            } else {                          // k=144 bias col (g==2), zeros (g==3)
                uint4 u = {0u, 0u, 0u, 0u};
                if (g == 2) u.x = 0x00003F80u;
                av = __builtin_bit_cast(bf16x8, u);
            }
            bf16x8 bv0 = __builtin_bit_cast(bf16x8, Wh4[n16 * 20 + ks * 4 + g]);
            bf16x8 bv1 = __builtin_bit_cast(bf16x8, Wh4[(16 + n16) * 20 + ks * 4 + g]);
            qa0 = MFMA_(av, bv0, qa0, 0, 0, 0);
            qa1 = MFMA_(av, bv1, qa1, 0, 0, 0);
        }
#pragma unroll
        for (int reg = 0; reg < 4; ++reg) {   // wave-local transpose (no barrier)
            int r = (w * 16 + g * 4 + reg) * 40;
            s_q[r + n16]      = f2bf(qa0[reg]);
            s_q[r + 16 + n16] = f2bf(qa1[reg]);   // d 24..31 zero via Whq rows
        }
    }
    const bf16x8 qf = *(const bf16x8*)&s_q[(w * 16 + n16) * 40 + g * 8];

    // ---- k-tile loop: V double-buffer (static phases), K direct-global ---
    const int koff = n16 * 4 + g;             // uint4 index inside K tile
    const int voff = n16 * 72 + g * 8;
    f32x4 acc0 = zf, acc1 = zf;

    auto phase = [&](ushort* vbuf, int ktile) {
        *(uint2*)&vbuf[stoff] = vreg;
        __syncthreads();
        vreg = Vb2[(((ktile + 1) & 31) << 9) + t];    // prefetch next V tile
        const uint4* Kt4 = Kb4 + (ktile << 8);
        bf16x8 a0 = __builtin_bit_cast(bf16x8, Kt4[koff]);
        bf16x8 a1 = __builtin_bit_cast(bf16x8, Kt4[koff + 64]);
        bf16x8 a2 = __builtin_bit_cast(bf16x8, Kt4[koff + 128]);
        bf16x8 a3 = __builtin_bit_cast(bf16x8, Kt4[koff + 192]);
        __builtin_amdgcn_s_setprio(1);
        f32x4 c0 = MFMA_(a0, qf, zf, 0, 0, 0);
        f32x4 c1 = MFMA_(a1, qf, zf, 0, 0, 0);
        f32x4 c2 = MFMA_(a2, qf, zf, 0, 0, 0);
        f32x4 c3 = MFMA_(a3, qf, zf, 0, 0, 0);
        __builtin_amdgcn_s_setprio(0);
        // tanh -> packed bf16 words: W[strip][pair], lane holds
        // P[q=n16][s = strip*16 + g*4 + 2*pair + {0,1}]
        uint W0p0 = tanh2_pack(c0[0], c0[1]);
        uint W0p1 = tanh2_pack(c0[2], c0[3]);
        uint W1p0 = tanh2_pack(c1[0], c1[1]);
        uint W1p1 = tanh2_pack(c1[2], c1[3]);
        uint W2p0 = tanh2_pack(c2[0], c2[1]);
        uint W2p1 = tanh2_pack(c2[2], c2[3]);
        uint W3p0 = tanh2_pack(c3[0], c3[1]);
        uint W3p1 = tanh2_pack(c3[2], c3[3]);
        // butterfly: bit5 (strip-pair) then bit4 -> PV A-frags in-register.
        swap32(W0p0, W1p0);
        swap32(W2p0, W3p0);
        swap32(W0p1, W1p1);
        swap32(W2p1, W3p1);
        swap16(W0p0, W1p0, hi16);
        swap16(W2p0, W3p0, hi16);
        swap16(W0p1, W1p1, hi16);
        swap16(W2p1, W3p1, hi16);
        uint4 ap0u, ap1u;
        ap0u.x = W0p0; ap0u.y = W0p1; ap0u.z = W1p0; ap0u.w = W1p1;
        ap1u.x = W2p0; ap1u.y = W2p1; ap1u.z = W3p0; ap1u.w = W3p1;
        bf16x8 ap0 = __builtin_bit_cast(bf16x8, ap0u);
        bf16x8 ap1 = __builtin_bit_cast(bf16x8, ap1u);
        // PV
        bf16x8 vb00 = *(const bf16x8*)&vbuf[voff];
        bf16x8 vb01 = *(const bf16x8*)&vbuf[voff + 32];
        bf16x8 vb10 = *(const bf16x8*)&vbuf[1152 + voff];
        bf16x8 vb11 = *(const bf16x8*)&vbuf[1152 + voff + 32];
        __builtin_amdgcn_s_setprio(1);
        acc0 = MFMA_(ap0, vb00, acc0, 0, 0, 0);
        acc0 = MFMA_(ap1, vb01, acc0, 0, 0, 0);
        acc1 = MFMA_(ap0, vb10, acc1, 0, 0, 0);
        acc1 = MFMA_(ap1, vb11, acc1, 0, 0, 0);
        __builtin_amdgcn_s_setprio(0);
    };
    for (int kt = 0; kt < 32; kt += 2) {
        phase(s_vt, kt);
        phase(s_vt + 2304, kt + 1);
    }

    // ---- epilogue: ctx -> Cb bf16 (s_ctx aliases s_q/s_vt; barrier both) --
    __syncthreads();
#pragma unroll
    for (int reg = 0; reg < 4; ++reg) {
        int row = w * 16 + g * 4 + reg;
        s_ctx[row * 28 + n16] = acc0[reg];
        if (n16 < 8) s_ctx[row * 28 + 16 + n16] = acc1[reg];
    }
    __syncthreads();
    if (t < 384) {
        int r = t / 3, c = t % 3;             // 3 x uint4 (8 bf16) per row
        const float* src = &s_ctx[r * 28 + c * 8];
        uint4 u;
        u.x = pack2(src[0], src[1]); u.y = pack2(src[2], src[3]);
        u.z = pack2(src[4], src[5]); u.w = pack2(src[6], src[7]);
        *(uint4*)&Cb[(size_t)(b * S_ + row0 + r) * 160 + h * 24 + c * 8] = u;
    }
}

// ---------------------------------------------------------------------------
// outln: out = LN(ctx @ Wl^T + lb + residual) * g + beta.
// ctx comes in as bf16 Cb[16384][160] -> pure uint4 LDS staging.
// ---------------------------------------------------------------------------
__global__ __launch_bounds__(512)
void outln_kernel(const float* __restrict__ Qres, const ushort* __restrict__ Wlp,
                  const ushort* __restrict__ Cb,
                  const float* __restrict__ lg, const float* __restrict__ lbeta,
                  float* __restrict__ io) {
    __shared__ __attribute__((aligned(16))) ushort s_a[64 * 168];
    __shared__ __attribute__((aligned(16))) ushort s_w[144 * 168];
    __shared__ float s_red[2][2][64];
    const int t = threadIdx.x;
    const int w = t >> 6, n16 = t & 15, g = (t >> 4) & 3;
    const int wq = w & 3, half = w >> 2;
    const int nt_base = half * 5, nt_cnt = half ? 4 : 5;
    const int row0 = blockIdx.x * 64;

    const ushort* Cr = Cb + (size_t)row0 * 160;
    for (int idx = t; idx < 1152; idx += 512) {     // cols 0..143 only
        int r = idx / 18, c8 = (idx % 18) * 8;
        *(uint4*)&s_a[r * 168 + c8] = *(const uint4*)&Cr[r * 160 + c8];
    }
    if (t < 64) {
        uint4 pad = {0x00003F80u, 0u, 0u, 0u};
        uint4 z4  = {0u, 0u, 0u, 0u};
        *(uint4*)&s_a[t * 168 + 144] = pad;
        *(uint4*)&s_a[t * 168 + 152] = z4;
    }
    for (int idx = t; idx < 2880; idx += 512) {
        int r = idx / 20, c8 = (idx % 20) * 8;
        *(uint4*)&s_w[r * 168 + c8] = *(const uint4*)&Wlp[r * 160 + c8];
    }
    __syncthreads();

    f32x4 acc[5];
#pragma unroll
    for (int j = 0; j < 5; ++j) acc[j] = (f32x4){0.f, 0.f, 0.f, 0.f};
#pragma unroll
    for (int ks = 0; ks < 5; ++ks) {
        bf16x8 av = *(const bf16x8*)&s_a[(wq * 16 + n16) * 168 + ks * 32 + g * 8];
        for (int j = 0; j < nt_cnt; ++j) {
            bf16x8 bv = *(const bf16x8*)&s_w[((nt_base + j) * 16 + n16) * 168 + ks * 32 + g * 8];
            acc[j] = MFMA_(av, bv, acc[j], 0, 0, 0);
        }
    }
    float vals[5][4], s1[4] = {0, 0, 0, 0}, s2[4] = {0, 0, 0, 0};
    for (int j = 0; j < nt_cnt; ++j) {
        int d = (nt_base + j) * 16 + n16;
#pragma unroll
        for (int reg = 0; reg < 4; ++reg) {
            int row = row0 + wq * 16 + g * 4 + reg;
            float v = acc[j][reg] + Qres[(size_t)row * DM_ + d];
            vals[j][reg] = v;
            s1[reg] += v; s2[reg] = fmaf(v, v, s2[reg]);
        }
    }
#pragma unroll
    for (int off = 1; off < 16; off <<= 1) {
#pragma unroll
        for (int reg = 0; reg < 4; ++reg) {
            s1[reg] += __shfl_xor(s1[reg], off);
            s2[reg] += __shfl_xor(s2[reg], off);
        }
    }
    if (n16 == 0) {
#pragma unroll
        for (int reg = 0; reg < 4; ++reg) {
            int rr = wq * 16 + g * 4 + reg;
            s_red[half][0][rr] = s1[reg];
            s_red[half][1][rr] = s2[reg];
        }
    }
    __syncthreads();
    float mu[4], rs[4];
#pragma unroll
    for (int reg = 0; reg < 4; ++reg) {
        int rr = wq * 16 + g * 4 + reg;
        float S1 = s_red[0][0][rr] + s_red[1][0][rr];
        float S2 = s_red[0][1][rr] + s_red[1][1][rr];
        float m = S1 * (1.f / 144.f);
        mu[reg] = m;
        rs[reg] = rsqrtf(S2 * (1.f / 144.f) - m * m + 1e-5f);
    }
    for (int j = 0; j < nt_cnt; ++j) {
        int d = (nt_base + j) * 16 + n16;
        float gv = lg[d], bv = lbeta[d];
#pragma unroll
        for (int reg = 0; reg < 4; ++reg) {
            int row = row0 + wq * 16 + g * 4 + reg;
            io[(size_t)row * DM_ + d] = (vals[j][reg] - mu[reg]) * rs[reg] * gv + bv;
        }
    }
}

// ---------------------------------------------------------------------------
extern "C" void kernel_launch(void* const* d_in, const int* in_sizes, int n_in,
                              void* d_out, int out_size, void* d_ws, size_t ws_size,
                              hipStream_t stream) {
    const float* Q     = (const float*)d_in[0];
    const float* K     = (const float*)d_in[1];
    const float* V     = (const float*)d_in[2];
    // d_in[3] = attn_mask: dead code in the reference, ignored.
    const float* Wq_w  = (const float*)d_in[4];
    const float* Wq_b  = (const float*)d_in[5];
    const float* lin_w = (const float*)d_in[6];
    const float* lin_b = (const float*)d_in[7];
    const float* ln_g  = (const float*)d_in[8];
    const float* ln_b  = (const float*)d_in[9];
    float* out = (float*)d_out;

    ushort* Ktt = (ushort*)d_ws;                            // 6,291,456 B
    ushort* Vtt = (ushort*)((char*)d_ws + 6291456);         // 6,291,456 B
    ushort* Whq = (ushort*)((char*)d_ws + 12582912);        // 61,440 B
    ushort* Wlp = (ushort*)((char*)d_ws + 12644352);        // 46,080 B
    ushort* Cb  = (ushort*)((char*)d_ws + 12690432);        // 5,242,880 B

    prep_kernel<<<1746, 256, 0, stream>>>(K, V, Wq_w, Wq_b, lin_w, lin_b,
                                          Ktt, Vtt, Whq, Wlp);
    attn_kernel<<<dim3(S_ / 128, H_, B_), 512, 0, stream>>>(Q, Whq, Ktt, Vtt, Cb);
    outln_kernel<<<(B_ * S_) / 64, 512, 0, stream>>>(Q, Wlp, Cb, ln_g, ln_b, out);
}

// Round 4
// 263.675 us; speedup vs baseline: 1.0291x; 1.0291x over previous
//
#include <hip/hip_runtime.h>
#include <hip/hip_bf16.h>

#define B_  8
#define S_  2048
#define H_  6
#define DK_ 24
#define DM_ 144

// tanh(SCALE*c) ~= c*(K0 + K1*t + K2*t^2), t = c^2, SCALE = 0.1/sqrt(24).
#define TK0  2.0412414523193153e-02f
#define TK1 -2.8350575726379381e-06f
#define TK2  4.7250959543965635e-10f

typedef __bf16 bf16x8 __attribute__((ext_vector_type(8)));
typedef __bf16 bf16x2 __attribute__((ext_vector_type(2)));
typedef float  f32x4  __attribute__((ext_vector_type(4)));
typedef float  f32x2  __attribute__((ext_vector_type(2)));

#define MFMA_ __builtin_amdgcn_mfma_f32_16x16x32_bf16

__device__ __forceinline__ unsigned short f2bf(float f) {
    return __builtin_bit_cast(unsigned short, (__bf16)f);
}
__device__ __forceinline__ uint pack2(float a, float b) {
    bf16x2 v; v[0] = (__bf16)a; v[1] = (__bf16)b;
    return __builtin_bit_cast(uint, v);
}
// packed tanh on a pair -> packed bf16 word (v_pk_mul_f32 / v_pk_fma_f32).
__device__ __forceinline__ uint tanh2_pack(float a, float b) {
    f32x2 c; c[0] = a; c[1] = b;
    f32x2 t = c * c;
    f32x2 u = t * TK2 + TK1;
    u = t * u + TK0;
    f32x2 r = c * u;
    return pack2(r[0], r[1]);
}

// lane-bit-5 swap: x' <- lower-32-half data of {x,y}; y' <- upper-half data.
__device__ __forceinline__ void swap32(uint &x, uint &y) {
    auto r = __builtin_amdgcn_permlane32_swap(x, y, false, false);
    x = r[0]; y = r[1];
}
// lane-bit-4 swap: x' <- bit4==0 data of {x,y}; y' <- bit4==1 data.
__device__ __forceinline__ void swap16(uint &x, uint &y, bool hi16) {
#if __has_builtin(__builtin_amdgcn_permlane16_swap)
    (void)hi16;
    auto r = __builtin_amdgcn_permlane16_swap(x, y, false, false);
    x = r[0]; y = r[1];
#else
    uint xs = __builtin_amdgcn_ds_swizzle(x, 0x401F);   // lane ^ 16
    uint ys = __builtin_amdgcn_ds_swizzle(y, 0x401F);
    uint nx = hi16 ? ys : x;
    uint ny = hi16 ? y : xs;
    x = nx; y = ny;
#endif
}

// ---------------------------------------------------------------------------
// prep: fused weight prep + K/V retile (one dispatch).
// blocks 0..1535   : K f32 -> Ktt[bh][kt][64 s][32 dk] bf16 (cols 24..31 zero)
//                    V f32 -> Vtt[bh][kt][32 d][64 s] bf16 (rows 24..31 zero)
// blocks 1536..1745: Whq[6][32][160] bf16 (head-sliced Wq, bias at k=144) and
//                    Wlp[144][160] bf16 (lin_w, bias at k=144).
// ---------------------------------------------------------------------------
__global__ __launch_bounds__(256)
void prep_kernel(const float* __restrict__ K, const float* __restrict__ V,
                 const float* __restrict__ Wq, const float* __restrict__ Wqb,
                 const float* __restrict__ Wl, const float* __restrict__ lb,
                 ushort* __restrict__ Ktt, ushort* __restrict__ Vtt,
                 ushort* __restrict__ Whq, ushort* __restrict__ Wlp) {
    __shared__ float sv[64 * 25];
    const int t = threadIdx.x;
    const int bid = blockIdx.x;
    if (bid >= 1536) {                        // ---- weight part ----
        int i = (bid - 1536) * 256 + t;
        if (i < 30720) {                      // Whq: 6*32*160
            int h = i / 5120, rem = i % 5120;
            int d = rem / 160, c = rem % 160;
            float v = 0.f;
            if (d < DK_) {
                if (c < DM_)       v = Wq[(h * DK_ + d) * DM_ + c];
                else if (c == DM_) v = Wqb[h * DK_ + d];
            }
            Whq[i] = f2bf(v);
        } else if (i < 53760) {               // Wlp: 144*160
            int j = i - 30720;
            int r = j / 160, c = j % 160;
            float v = (c < DM_) ? Wl[r * DM_ + c] : (c == DM_ ? lb[r] : 0.f);
            Wlp[j] = f2bf(v);
        }
        return;
    }
    // ---- KV part ----
    const int kt = bid & 31, h = (bid >> 5) % H_, b = bid / (32 * H_);
    const int bh = b * H_ + h;
    const size_t tile = (size_t)(bh * 32 + kt);
    const float4* Ks = (const float4*)(K + ((size_t)bh * S_ + kt * 64) * DK_);
    ushort* Ko = Ktt + tile * 2048;
    for (int idx = t; idx < 384; idx += 256) {
        int r = idx / 6, c4 = (idx % 6) * 4;
        float4 v = Ks[idx];
        ushort4 u; u.x = f2bf(v.x); u.y = f2bf(v.y); u.z = f2bf(v.z); u.w = f2bf(v.w);
        *(ushort4*)&Ko[r * 32 + c4] = u;
    }
    if (t < 64) { uint4 z = {0u,0u,0u,0u}; *(uint4*)&Ko[t * 32 + 24] = z; }
    const float4* Vs = (const float4*)(V + ((size_t)bh * S_ + kt * 64) * DK_);
    for (int idx = t; idx < 384; idx += 256) {
        int r = idx / 6, c4 = (idx % 6) * 4;
        *(float4*)&sv[r * 25 + c4] = Vs[idx];
    }
    __syncthreads();
    int d = t >> 3, s8 = (t & 7) * 8;
    uint4 o = {0u,0u,0u,0u};
    if (d < DK_) {
        o.x = pack2(sv[(s8 + 0) * 25 + d], sv[(s8 + 1) * 25 + d]);
        o.y = pack2(sv[(s8 + 2) * 25 + d], sv[(s8 + 3) * 25 + d]);
        o.z = pack2(sv[(s8 + 4) * 25 + d], sv[(s8 + 5) * 25 + d]);
        o.w = pack2(sv[(s8 + 6) * 25 + d], sv[(s8 + 7) * 25 + d]);
    }
    ((uint4*)Vtt)[tile * 256 + t] = o;
}

// ---------------------------------------------------------------------------
// attn: fused qproj + tanh-attention.
// Block = 512 threads (8 waves) = 256 q-rows of one (b,h); wave owns 32 rows
// (two 16-row halves sharing the SAME K-strip and V-frag LDS reads -> LDS
// read traffic per q-row is HALF of the 16-row/wave version).
// Grid 384 = dim3(8,6,8); 2 blocks/CU resident (launch_bounds(512,4)).
// K/V in LDS, double-buffer (static phases), ONE barrier per k-tile.
// Staging: waves 0-3 -> K, waves 4-7 -> V (1 uint4 per thread per tile).
// P never touches LDS: QK^T frag -> PV A-frag via permlane32/16 butterfly.
// Output: bf16 ctx tile into Cb[16384][160] (outln-staging layout).
// ---------------------------------------------------------------------------
__global__ __launch_bounds__(512, 4)
void attn_kernel(const float* __restrict__ Q, const ushort* __restrict__ Whq,
                 const ushort* __restrict__ Ktt, const ushort* __restrict__ Vtt,
                 ushort* __restrict__ Cb) {
    __shared__ __attribute__((aligned(16))) char smem[39936];
    ushort* s_q  = (ushort*)smem;             // 256 x pitch40    [0, 20480)
    ushort* s_k  = (ushort*)(smem + 20480);   // 2 x 64 x pitch40 [20480, 30720)
    ushort* s_vt = (ushort*)(smem + 30720);   // 2 x 32 x pitch72 [30720, 39936)
    float*  s_ctx = (float*)smem;             // epilogue alias: 256 x 28 f32

    const int t = threadIdx.x;
    const int w = t >> 6, n16 = t & 15, g = (t >> 4) & 3;
    const bool hi16 = (t & 16) != 0;
    const int qp = blockIdx.x, h = blockIdx.y, b = blockIdx.z;
    const int bh = b * H_ + h;
    const int row0 = qp * 256;

    const uint4* Kb4 = (const uint4*)Ktt + (size_t)bh * 8192;   // 32 tiles x 256
    const uint4* Vb4 = (const uint4*)Vtt + (size_t)bh * 8192;

    // staging role: waves 0-3 -> K (t<256), waves 4-7 -> V
    const int t2 = t & 255;
    const int stoff = (t < 256) ? ((t2 >> 2) * 40 + (t2 & 3) * 8)
                                : ((t2 >> 3) * 72 + (t2 & 7) * 8);
    uint4 sreg = (t < 256) ? Kb4[t2] : Vb4[t2];       // preload tile 0

    // ---- Phase A: q = Q @ Whq^T + bias (k=144 col), two 16-row halves ----
    const f32x4 zf = {0.f, 0.f, 0.f, 0.f};
    const uint4* Wh4 = (const uint4*)Whq + h * 640;
#pragma unroll
    for (int hf = 0; hf < 2; ++hf) {
        const float* Qr = Q + (size_t)(b * S_ + row0 + w * 32 + hf * 16 + n16) * DM_;
        f32x4 qa0 = zf, qa1 = zf;
#pragma unroll
        for (int ks = 0; ks < 5; ++ks) {
            bf16x8 av;
            if (ks < 4 || g < 2) {            // real cols (ks=4,g<2 -> 128..143)
                float4 f0 = *(const float4*)&Qr[ks * 32 + g * 8];
                float4 f1 = *(const float4*)&Qr[ks * 32 + g * 8 + 4];
                uint4 u;
                u.x = pack2(f0.x, f0.y); u.y = pack2(f0.z, f0.w);
                u.z = pack2(f1.x, f1.y); u.w = pack2(f1.z, f1.w);
                av = __builtin_bit_cast(bf16x8, u);
            } else {                          // k=144 bias col (g==2), zeros (g==3)
                uint4 u = {0u, 0u, 0u, 0u};
                if (g == 2) u.x = 0x00003F80u;
                av = __builtin_bit_cast(bf16x8, u);
            }
            bf16x8 bv0 = __builtin_bit_cast(bf16x8, Wh4[n16 * 20 + ks * 4 + g]);
            bf16x8 bv1 = __builtin_bit_cast(bf16x8, Wh4[(16 + n16) * 20 + ks * 4 + g]);
            qa0 = MFMA_(av, bv0, qa0, 0, 0, 0);
            qa1 = MFMA_(av, bv1, qa1, 0, 0, 0);
        }
#pragma unroll
        for (int reg = 0; reg < 4; ++reg) {   // wave-local transpose (no barrier)
            int r = (w * 32 + hf * 16 + g * 4 + reg) * 40;
            s_q[r + n16]      = f2bf(qa0[reg]);
            s_q[r + 16 + n16] = f2bf(qa1[reg]);   // d 24..31 zero via Whq rows
        }
    }
    const bf16x8 qf0 = *(const bf16x8*)&s_q[(w * 32 + n16) * 40 + g * 8];
    const bf16x8 qf1 = *(const bf16x8*)&s_q[(w * 32 + 16 + n16) * 40 + g * 8];

    // ---- k-tile loop: K/V double-buffer (static phases) ------------------
    const int aoff = n16 * 40 + g * 8;        // hoisted LDS read offsets
    const int voff = n16 * 72 + g * 8;
    f32x4 acc00 = zf, acc01 = zf, acc10 = zf, acc11 = zf;

    auto phase = [&](ushort* kbuf, ushort* vbuf, int ktile) {
        *(uint4*)(((t < 256) ? kbuf : vbuf) + stoff) = sreg;
        __syncthreads();
        {   // prefetch next tile AFTER the barrier
            int nt = ((ktile + 1) & 31) * 256;
            sreg = (t < 256) ? Kb4[nt + t2] : Vb4[nt + t2];
        }
        // K strips: read ONCE, reused by both q-halves
        bf16x8 a0 = *(const bf16x8*)&kbuf[aoff];
        bf16x8 a1 = *(const bf16x8*)&kbuf[640 + aoff];
        bf16x8 a2 = *(const bf16x8*)&kbuf[1280 + aoff];
        bf16x8 a3 = *(const bf16x8*)&kbuf[1920 + aoff];
        // ---- half 0: QK^T -> tanh -> butterfly -> ap frags ----
        __builtin_amdgcn_s_setprio(1);
        f32x4 c0 = MFMA_(a0, qf0, zf, 0, 0, 0);
        f32x4 c1 = MFMA_(a1, qf0, zf, 0, 0, 0);
        f32x4 c2 = MFMA_(a2, qf0, zf, 0, 0, 0);
        f32x4 c3 = MFMA_(a3, qf0, zf, 0, 0, 0);
        __builtin_amdgcn_s_setprio(0);
        uint W0p0 = tanh2_pack(c0[0], c0[1]);
        uint W0p1 = tanh2_pack(c0[2], c0[3]);
        uint W1p0 = tanh2_pack(c1[0], c1[1]);
        uint W1p1 = tanh2_pack(c1[2], c1[3]);
        uint W2p0 = tanh2_pack(c2[0], c2[1]);
        uint W2p1 = tanh2_pack(c2[2], c2[3]);
        uint W3p0 = tanh2_pack(c3[0], c3[1]);
        uint W3p1 = tanh2_pack(c3[2], c3[3]);
        swap32(W0p0, W1p0);
        swap32(W2p0, W3p0);
        swap32(W0p1, W1p1);
        swap32(W2p1, W3p1);
        swap16(W0p0, W1p0, hi16);
        swap16(W2p0, W3p0, hi16);
        swap16(W0p1, W1p1, hi16);
        swap16(W2p1, W3p1, hi16);
        uint4 apu;
        apu.x = W0p0; apu.y = W0p1; apu.z = W1p0; apu.w = W1p1;
        bf16x8 ap0h0 = __builtin_bit_cast(bf16x8, apu);
        apu.x = W2p0; apu.y = W2p1; apu.z = W3p0; apu.w = W3p1;
        bf16x8 ap1h0 = __builtin_bit_cast(bf16x8, apu);
        // ---- half 1: QK^T (reuse K strips) -> tanh -> butterfly ----
        __builtin_amdgcn_s_setprio(1);
        c0 = MFMA_(a0, qf1, zf, 0, 0, 0);
        c1 = MFMA_(a1, qf1, zf, 0, 0, 0);
        c2 = MFMA_(a2, qf1, zf, 0, 0, 0);
        c3 = MFMA_(a3, qf1, zf, 0, 0, 0);
        __builtin_amdgcn_s_setprio(0);
        W0p0 = tanh2_pack(c0[0], c0[1]);
        W0p1 = tanh2_pack(c0[2], c0[3]);
        W1p0 = tanh2_pack(c1[0], c1[1]);
        W1p1 = tanh2_pack(c1[2], c1[3]);
        W2p0 = tanh2_pack(c2[0], c2[1]);
        W2p1 = tanh2_pack(c2[2], c2[3]);
        W3p0 = tanh2_pack(c3[0], c3[1]);
        W3p1 = tanh2_pack(c3[2], c3[3]);
        swap32(W0p0, W1p0);
        swap32(W2p0, W3p0);
        swap32(W0p1, W1p1);
        swap32(W2p1, W3p1);
        swap16(W0p0, W1p0, hi16);
        swap16(W2p0, W3p0, hi16);
        swap16(W0p1, W1p1, hi16);
        swap16(W2p1, W3p1, hi16);
        apu.x = W0p0; apu.y = W0p1; apu.z = W1p0; apu.w = W1p1;
        bf16x8 ap0h1 = __builtin_bit_cast(bf16x8, apu);
        apu.x = W2p0; apu.y = W2p1; apu.z = W3p0; apu.w = W3p1;
        bf16x8 ap1h1 = __builtin_bit_cast(bf16x8, apu);
        // ---- PV: V frags read ONCE, reused by both halves ----
        bf16x8 vb00 = *(const bf16x8*)&vbuf[voff];
        bf16x8 vb01 = *(const bf16x8*)&vbuf[voff + 32];
        bf16x8 vb10 = *(const bf16x8*)&vbuf[1152 + voff];
        bf16x8 vb11 = *(const bf16x8*)&vbuf[1152 + voff + 32];
        __builtin_amdgcn_s_setprio(1);
        acc00 = MFMA_(ap0h0, vb00, acc00, 0, 0, 0);
        acc00 = MFMA_(ap1h0, vb01, acc00, 0, 0, 0);
        acc01 = MFMA_(ap0h0, vb10, acc01, 0, 0, 0);
        acc01 = MFMA_(ap1h0, vb11, acc01, 0, 0, 0);
        acc10 = MFMA_(ap0h1, vb00, acc10, 0, 0, 0);
        acc10 = MFMA_(ap1h1, vb01, acc10, 0, 0, 0);
        acc11 = MFMA_(ap0h1, vb10, acc11, 0, 0, 0);
        acc11 = MFMA_(ap1h1, vb11, acc11, 0, 0, 0);
        __builtin_amdgcn_s_setprio(0);
    };
    for (int kt = 0; kt < 32; kt += 2) {
        phase(s_k, s_vt, kt);
        phase(s_k + 2560, s_vt + 2304, kt + 1);
    }

    // ---- epilogue: ctx -> Cb bf16 (s_ctx aliases s_q/s_k; barrier both) ---
    __syncthreads();
#pragma unroll
    for (int reg = 0; reg < 4; ++reg) {
        int r0 = w * 32 + g * 4 + reg;
        s_ctx[r0 * 28 + n16] = acc00[reg];
        if (n16 < 8) s_ctx[r0 * 28 + 16 + n16] = acc01[reg];
        int r1 = r0 + 16;
        s_ctx[r1 * 28 + n16] = acc10[reg];
        if (n16 < 8) s_ctx[r1 * 28 + 16 + n16] = acc11[reg];
    }
    __syncthreads();
    for (int idx = t; idx < 768; idx += 512) {
        int r = idx / 3, c = idx % 3;         // 3 x uint4 (8 bf16) per row
        const float* src = &s_ctx[r * 28 + c * 8];
        uint4 u;
        u.x = pack2(src[0], src[1]); u.y = pack2(src[2], src[3]);
        u.z = pack2(src[4], src[5]); u.w = pack2(src[6], src[7]);
        *(uint4*)&Cb[(size_t)(b * S_ + row0 + r) * 160 + h * 24 + c * 8] = u;
    }
}

// ---------------------------------------------------------------------------
// outln: out = LN(ctx @ Wl^T + lb + residual) * g + beta.
// ctx comes in as bf16 Cb[16384][160] -> pure uint4 LDS staging.
// ---------------------------------------------------------------------------
__global__ __launch_bounds__(512)
void outln_kernel(const float* __restrict__ Qres, const ushort* __restrict__ Wlp,
                  const ushort* __restrict__ Cb,
                  const float* __restrict__ lg, const float* __restrict__ lbeta,
                  float* __restrict__ io) {
    __shared__ __attribute__((aligned(16))) ushort s_a[64 * 168];
    __shared__ __attribute__((aligned(16))) ushort s_w[144 * 168];
    __shared__ float s_red[2][2][64];
    const int t = threadIdx.x;
    const int w = t >> 6, n16 = t & 15, g = (t >> 4) & 3;
    const int wq = w & 3, half = w >> 2;
    const int nt_base = half * 5, nt_cnt = half ? 4 : 5;
    const int row0 = blockIdx.x * 64;

    const ushort* Cr = Cb + (size_t)row0 * 160;
    for (int idx = t; idx < 1152; idx += 512) {     // cols 0..143 only
        int r = idx / 18, c8 = (idx % 18) * 8;
        *(uint4*)&s_a[r * 168 + c8] = *(const uint4*)&Cr[r * 160 + c8];
    }
    if (t < 64) {
        uint4 pad = {0x00003F80u, 0u, 0u, 0u};
        uint4 z4  = {0u, 0u, 0u, 0u};
        *(uint4*)&s_a[t * 168 + 144] = pad;
        *(uint4*)&s_a[t * 168 + 152] = z4;
    }
    for (int idx = t; idx < 2880; idx += 512) {
        int r = idx / 20, c8 = (idx % 20) * 8;
        *(uint4*)&s_w[r * 168 + c8] = *(const uint4*)&Wlp[r * 160 + c8];
    }
    __syncthreads();

    f32x4 acc[5];
#pragma unroll
    for (int j = 0; j < 5; ++j) acc[j] = (f32x4){0.f, 0.f, 0.f, 0.f};
#pragma unroll
    for (int ks = 0; ks < 5; ++ks) {
        bf16x8 av = *(const bf16x8*)&s_a[(wq * 16 + n16) * 168 + ks * 32 + g * 8];
        for (int j = 0; j < nt_cnt; ++j) {
            bf16x8 bv = *(const bf16x8*)&s_w[((nt_base + j) * 16 + n16) * 168 + ks * 32 + g * 8];
            acc[j] = MFMA_(av, bv, acc[j], 0, 0, 0);
        }
    }
    float vals[5][4], s1[4] = {0, 0, 0, 0}, s2[4] = {0, 0, 0, 0};
    for (int j = 0; j < nt_cnt; ++j) {
        int d = (nt_base + j) * 16 + n16;
#pragma unroll
        for (int reg = 0; reg < 4; ++reg) {
            int row = row0 + wq * 16 + g * 4 + reg;
            float v = acc[j][reg] + Qres[(size_t)row * DM_ + d];
            vals[j][reg] = v;
            s1[reg] += v; s2[reg] = fmaf(v, v, s2[reg]);
        }
    }
#pragma unroll
    for (int off = 1; off < 16; off <<= 1) {
#pragma unroll
        for (int reg = 0; reg < 4; ++reg) {
            s1[reg] += __shfl_xor(s1[reg], off);
            s2[reg] += __shfl_xor(s2[reg], off);
        }
    }
    if (n16 == 0) {
#pragma unroll
        for (int reg = 0; reg < 4; ++reg) {
            int rr = wq * 16 + g * 4 + reg;
            s_red[half][0][rr] = s1[reg];
            s_red[half][1][rr] = s2[reg];
        }
    }
    __syncthreads();
    float mu[4], rs[4];
#pragma unroll
    for (int reg = 0; reg < 4; ++reg) {
        int rr = wq * 16 + g * 4 + reg;
        float S1 = s_red[0][0][rr] + s_red[1][0][rr];
        float S2 = s_red[0][1][rr] + s_red[1][1][rr];
        float m = S1 * (1.f / 144.f);
        mu[reg] = m;
        rs[reg] = rsqrtf(S2 * (1.f / 144.f) - m * m + 1e-5f);
    }
    for (int j = 0; j < nt_cnt; ++j) {
        int d = (nt_base + j) * 16 + n16;
        float gv = lg[d], bv = lbeta[d];
#pragma unroll
        for (int reg = 0; reg < 4; ++reg) {
            int row = row0 + wq * 16 + g * 4 + reg;
            io[(size_t)row * DM_ + d] = (vals[j][reg] - mu[reg]) * rs[reg] * gv + bv;
        }
    }
}

// ---------------------------------------------------------------------------
extern "C" void kernel_launch(void* const* d_in, const int* in_sizes, int n_in,
                              void* d_out, int out_size, void* d_ws, size_t ws_size,
                              hipStream_t stream) {
    const float* Q     = (const float*)d_in[0];
    const float* K     = (const float*)d_in[1];
    const float* V     = (const float*)d_in[2];
    // d_in[3] = attn_mask: dead code in the reference, ignored.
    const float* Wq_w  = (const float*)d_in[4];
    const float* Wq_b  = (const float*)d_in[5];
    const float* lin_w = (const float*)d_in[6];
    const float* lin_b = (const float*)d_in[7];
    const float* ln_g  = (const float*)d_in[8];
    const float* ln_b  = (const float*)d_in[9];
    float* out = (float*)d_out;

    ushort* Ktt = (ushort*)d_ws;                            // 6,291,456 B
    ushort* Vtt = (ushort*)((char*)d_ws + 6291456);         // 6,291,456 B
    ushort* Whq = (ushort*)((char*)d_ws + 12582912);        // 61,440 B
    ushort* Wlp = (ushort*)((char*)d_ws + 12644352);        // 46,080 B
    ushort* Cb  = (ushort*)((char*)d_ws + 12690432);        // 5,242,880 B

    prep_kernel<<<1746, 256, 0, stream>>>(K, V, Wq_w, Wq_b, lin_w, lin_b,
                                          Ktt, Vtt, Whq, Wlp);
    attn_kernel<<<dim3(S_ / 256, H_, B_), 512, 0, stream>>>(Q, Whq, Ktt, Vtt, Cb);
    outln_kernel<<<(B_ * S_) / 64, 512, 0, stream>>>(Q, Wlp, Cb, ln_g, ln_b, out);
}

// Round 5
// 253.224 us; speedup vs baseline: 1.0716x; 1.0413x over previous
//
#include <hip/hip_runtime.h>
#include <hip/hip_bf16.h>

#define B_  8
#define S_  2048
#define H_  6
#define DK_ 24
#define DM_ 144

// tanh(SCALE*c) ~= c*(K0 + K1*t + K2*t^2), t = c^2, SCALE = 0.1/sqrt(24).
#define TK0  2.0412414523193153e-02f
#define TK1 -2.8350575726379381e-06f
#define TK2  4.7250959543965635e-10f

typedef __bf16 bf16x8 __attribute__((ext_vector_type(8)));
typedef __bf16 bf16x2 __attribute__((ext_vector_type(2)));
typedef float  f32x4  __attribute__((ext_vector_type(4)));
typedef float  f32x2  __attribute__((ext_vector_type(2)));

#define MFMA_ __builtin_amdgcn_mfma_f32_16x16x32_bf16

__device__ __forceinline__ unsigned short f2bf(float f) {
    return __builtin_bit_cast(unsigned short, (__bf16)f);
}
__device__ __forceinline__ uint pack2(float a, float b) {
    bf16x2 v; v[0] = (__bf16)a; v[1] = (__bf16)b;
    return __builtin_bit_cast(uint, v);
}
// packed tanh on a pair -> packed bf16 word (v_pk_mul_f32 / v_pk_fma_f32).
__device__ __forceinline__ uint tanh2_pack(float a, float b) {
    f32x2 c; c[0] = a; c[1] = b;
    f32x2 t = c * c;
    f32x2 u = t * TK2 + TK1;
    u = t * u + TK0;
    f32x2 r = c * u;
    return pack2(r[0], r[1]);
}

// lane-bit-5 swap: x' <- lower-32-half data of {x,y}; y' <- upper-half data.
__device__ __forceinline__ void swap32(uint &x, uint &y) {
    auto r = __builtin_amdgcn_permlane32_swap(x, y, false, false);
    x = r[0]; y = r[1];
}
// lane-bit-4 swap: x' <- bit4==0 data of {x,y}; y' <- bit4==1 data.
__device__ __forceinline__ void swap16(uint &x, uint &y, bool hi16) {
#if __has_builtin(__builtin_amdgcn_permlane16_swap)
    (void)hi16;
    auto r = __builtin_amdgcn_permlane16_swap(x, y, false, false);
    x = r[0]; y = r[1];
#else
    uint xs = __builtin_amdgcn_ds_swizzle(x, 0x401F);   // lane ^ 16
    uint ys = __builtin_amdgcn_ds_swizzle(y, 0x401F);
    uint nx = hi16 ? ys : x;
    uint ny = hi16 ? y : xs;
    x = nx; y = ny;
#endif
}

// ---------------------------------------------------------------------------
// prep: fused weight prep + K/V retile (one dispatch).
// blocks 0..1535   : K f32 -> Ktt[bh][kt][64 s][32 dk] bf16 (cols 24..31 zero)
//                    V f32 -> Vtt[bh][kt][32 d][64 s] bf16 (rows 24..31 zero)
// blocks 1536..1745: Whq[6][32][160] bf16 (head-sliced Wq, bias at k=144) and
//                    Wlp[144][160] bf16 (lin_w, bias at k=144).
// ---------------------------------------------------------------------------
__global__ __launch_bounds__(256)
void prep_kernel(const float* __restrict__ K, const float* __restrict__ V,
                 const float* __restrict__ Wq, const float* __restrict__ Wqb,
                 const float* __restrict__ Wl, const float* __restrict__ lb,
                 ushort* __restrict__ Ktt, ushort* __restrict__ Vtt,
                 ushort* __restrict__ Whq, ushort* __restrict__ Wlp) {
    __shared__ float sv[64 * 25];
    const int t = threadIdx.x;
    const int bid = blockIdx.x;
    if (bid >= 1536) {                        // ---- weight part ----
        int i = (bid - 1536) * 256 + t;
        if (i < 30720) {                      // Whq: 6*32*160
            int h = i / 5120, rem = i % 5120;
            int d = rem / 160, c = rem % 160;
            float v = 0.f;
            if (d < DK_) {
                if (c < DM_)       v = Wq[(h * DK_ + d) * DM_ + c];
                else if (c == DM_) v = Wqb[h * DK_ + d];
            }
            Whq[i] = f2bf(v);
        } else if (i < 53760) {               // Wlp: 144*160
            int j = i - 30720;
            int r = j / 160, c = j % 160;
            float v = (c < DM_) ? Wl[r * DM_ + c] : (c == DM_ ? lb[r] : 0.f);
            Wlp[j] = f2bf(v);
        }
        return;
    }
    // ---- KV part ----
    const int kt = bid & 31, h = (bid >> 5) % H_, b = bid / (32 * H_);
    const int bh = b * H_ + h;
    const size_t tile = (size_t)(bh * 32 + kt);
    const float4* Ks = (const float4*)(K + ((size_t)bh * S_ + kt * 64) * DK_);
    ushort* Ko = Ktt + tile * 2048;
    for (int idx = t; idx < 384; idx += 256) {
        int r = idx / 6, c4 = (idx % 6) * 4;
        float4 v = Ks[idx];
        ushort4 u; u.x = f2bf(v.x); u.y = f2bf(v.y); u.z = f2bf(v.z); u.w = f2bf(v.w);
        *(ushort4*)&Ko[r * 32 + c4] = u;
    }
    if (t < 64) { uint4 z = {0u,0u,0u,0u}; *(uint4*)&Ko[t * 32 + 24] = z; }
    const float4* Vs = (const float4*)(V + ((size_t)bh * S_ + kt * 64) * DK_);
    for (int idx = t; idx < 384; idx += 256) {
        int r = idx / 6, c4 = (idx % 6) * 4;
        *(float4*)&sv[r * 25 + c4] = Vs[idx];
    }
    __syncthreads();
    int d = t >> 3, s8 = (t & 7) * 8;
    uint4 o = {0u,0u,0u,0u};
    if (d < DK_) {
        o.x = pack2(sv[(s8 + 0) * 25 + d], sv[(s8 + 1) * 25 + d]);
        o.y = pack2(sv[(s8 + 2) * 25 + d], sv[(s8 + 3) * 25 + d]);
        o.z = pack2(sv[(s8 + 4) * 25 + d], sv[(s8 + 5) * 25 + d]);
        o.w = pack2(sv[(s8 + 6) * 25 + d], sv[(s8 + 7) * 25 + d]);
    }
    ((uint4*)Vtt)[tile * 256 + t] = o;
}

// ---------------------------------------------------------------------------
// attn: fused qproj + tanh-attention.  (R2 geometry: 16 rows/wave.)
// Block = 512 threads (8 waves) = 128 q-rows of one (b,h); wave owns 16 rows.
// Grid 768 = 3 blocks/CU, LDS 38KB (s_q/s_ctx alias the chunk buffers),
// 24 waves/CU.
// K/V staged in 2-TILE CHUNKS, double-buffered -> ONE barrier per 2 k-tiles
// (16 barriers total).  Staging: waves 0-3 -> K, waves 4-7 -> V (2 uint4
// per thread per chunk).
// P never touches LDS: QK^T frag -> PV A-frag via permlane32/16 butterfly.
// Output: bf16 ctx tile into Cb[16384][160] (outln-staging layout).
// ---------------------------------------------------------------------------
__global__ __launch_bounds__(512, 6)
void attn_kernel(const float* __restrict__ Q, const ushort* __restrict__ Whq,
                 const ushort* __restrict__ Ktt, const ushort* __restrict__ Vtt,
                 ushort* __restrict__ Cb) {
    __shared__ __attribute__((aligned(16))) char smem[38912];
    ushort* s_k  = (ushort*)smem;             // 2 chunks x 2 x 2560 us [0,20480)B
    ushort* s_vt = (ushort*)(smem + 20480);   // 2 chunks x 2 x 2304 us [20480,38912)B
    ushort* s_q  = (ushort*)smem;             // phase-A alias: 128 x 40 (10240B)
    float*  s_ctx = (float*)smem;             // epilogue alias: 128 x 28 f32

    const int t = threadIdx.x;
    const int w = t >> 6, n16 = t & 15, g = (t >> 4) & 3;
    const bool hi16 = (t & 16) != 0;
    const int qp = blockIdx.x, h = blockIdx.y, b = blockIdx.z;
    const int bh = b * H_ + h;
    const int row0 = qp * 128;

    const uint4* Kb4 = (const uint4*)Ktt + (size_t)bh * 8192;   // 32 tiles x 256
    const uint4* Vb4 = (const uint4*)Vtt + (size_t)bh * 8192;

    // staging role: waves 0-3 -> K (t<256), waves 4-7 -> V
    const int t2 = t & 255;
    const bool isK = (t < 256);
    const int stoff = isK ? ((t2 >> 2) * 40 + (t2 & 3) * 8)
                          : ((t2 >> 3) * 72 + (t2 & 7) * 8);
    // preload chunk 0 (tiles 0,1)
    uint4 sreg0 = isK ? Kb4[t2] : Vb4[t2];
    uint4 sreg1 = isK ? Kb4[256 + t2] : Vb4[256 + t2];

    // ---- Phase A: q = Q @ Whq^T + bias (k=144 col), frags from global ----
    const f32x4 zf = {0.f, 0.f, 0.f, 0.f};
    const uint4* Wh4 = (const uint4*)Whq + h * 640;
    {
        const float* Qr = Q + (size_t)(b * S_ + row0 + w * 16 + n16) * DM_;
        f32x4 qa0 = zf, qa1 = zf;
#pragma unroll
        for (int ks = 0; ks < 5; ++ks) {
            bf16x8 av;
            if (ks < 4 || g < 2) {            // real cols (ks=4,g<2 -> 128..143)
                float4 f0 = *(const float4*)&Qr[ks * 32 + g * 8];
                float4 f1 = *(const float4*)&Qr[ks * 32 + g * 8 + 4];
                uint4 u;
                u.x = pack2(f0.x, f0.y); u.y = pack2(f0.z, f0.w);
                u.z = pack2(f1.x, f1.y); u.w = pack2(f1.z, f1.w);
                av = __builtin_bit_cast(bf16x8, u);
            } else {                          // k=144 bias col (g==2), zeros (g==3)
                uint4 u = {0u, 0u, 0u, 0u};
                if (g == 2) u.x = 0x00003F80u;
                av = __builtin_bit_cast(bf16x8, u);
            }
            bf16x8 bv0 = __builtin_bit_cast(bf16x8, Wh4[n16 * 20 + ks * 4 + g]);
            bf16x8 bv1 = __builtin_bit_cast(bf16x8, Wh4[(16 + n16) * 20 + ks * 4 + g]);
            qa0 = MFMA_(av, bv0, qa0, 0, 0, 0);
            qa1 = MFMA_(av, bv1, qa1, 0, 0, 0);
        }
#pragma unroll
        for (int reg = 0; reg < 4; ++reg) {   // wave-local transpose (no barrier)
            int r = (w * 16 + g * 4 + reg) * 40;
            s_q[r + n16]      = f2bf(qa0[reg]);
            s_q[r + 16 + n16] = f2bf(qa1[reg]);   // d 24..31 zero via Whq rows
        }
    }
    const bf16x8 qf = *(const bf16x8*)&s_q[(w * 16 + n16) * 40 + g * 8];
    __syncthreads();   // s_q aliases K chunk buffers: protect before staging

    // ---- k-loop: 16 chunks of 2 tiles, double-buffered, 1 barrier/chunk --
    const int aoff = n16 * 40 + g * 8;        // hoisted LDS read offsets
    const int voff = n16 * 72 + g * 8;
    f32x4 acc0 = zf, acc1 = zf;

    for (int c = 0; c < 16; ++c) {
        ushort* kc = s_k + (c & 1) * 5120;
        ushort* vc = s_vt + (c & 1) * 4608;
        if (isK) { *(uint4*)&kc[stoff] = sreg0; *(uint4*)&kc[2560 + stoff] = sreg1; }
        else     { *(uint4*)&vc[stoff] = sreg0; *(uint4*)&vc[2304 + stoff] = sreg1; }
        __syncthreads();
        {   // prefetch next chunk AFTER the barrier
            int nt = ((2 * c + 2) & 31) * 256;
            sreg0 = isK ? Kb4[nt + t2] : Vb4[nt + t2];
            sreg1 = isK ? Kb4[nt + 256 + t2] : Vb4[nt + 256 + t2];
        }
#pragma unroll
        for (int p = 0; p < 2; ++p) {
            const ushort* kp = kc + p * 2560;
            const ushort* vp = vc + p * 2304;
            // S strips -> P in registers
            bf16x8 a0 = *(const bf16x8*)&kp[aoff];
            bf16x8 a1 = *(const bf16x8*)&kp[640 + aoff];
            bf16x8 a2 = *(const bf16x8*)&kp[1280 + aoff];
            bf16x8 a3 = *(const bf16x8*)&kp[1920 + aoff];
            __builtin_amdgcn_s_setprio(1);
            f32x4 c0 = MFMA_(a0, qf, zf, 0, 0, 0);
            f32x4 c1 = MFMA_(a1, qf, zf, 0, 0, 0);
            f32x4 c2 = MFMA_(a2, qf, zf, 0, 0, 0);
            f32x4 c3 = MFMA_(a3, qf, zf, 0, 0, 0);
            __builtin_amdgcn_s_setprio(0);
            // tanh -> packed bf16 words: W[strip][pair], lane holds
            // P[q=n16][s = strip*16 + g*4 + 2*pair + {0,1}]
            uint W0p0 = tanh2_pack(c0[0], c0[1]);
            uint W0p1 = tanh2_pack(c0[2], c0[3]);
            uint W1p0 = tanh2_pack(c1[0], c1[1]);
            uint W1p1 = tanh2_pack(c1[2], c1[3]);
            uint W2p0 = tanh2_pack(c2[0], c2[1]);
            uint W2p1 = tanh2_pack(c2[2], c2[3]);
            uint W3p0 = tanh2_pack(c3[0], c3[1]);
            uint W3p1 = tanh2_pack(c3[2], c3[3]);
            // butterfly: bit5 then bit4 -> PV A-frags in-register.
            // ap0 lane g = P[q=n16][s=g*8+0..7], ap1 = s=32+g*8+0..7.
            swap32(W0p0, W1p0);
            swap32(W2p0, W3p0);
            swap32(W0p1, W1p1);
            swap32(W2p1, W3p1);
            swap16(W0p0, W1p0, hi16);
            swap16(W2p0, W3p0, hi16);
            swap16(W0p1, W1p1, hi16);
            swap16(W2p1, W3p1, hi16);
            uint4 ap0u, ap1u;
            ap0u.x = W0p0; ap0u.y = W0p1; ap0u.z = W1p0; ap0u.w = W1p1;
            ap1u.x = W2p0; ap1u.y = W2p1; ap1u.z = W3p0; ap1u.w = W3p1;
            bf16x8 ap0 = __builtin_bit_cast(bf16x8, ap0u);
            bf16x8 ap1 = __builtin_bit_cast(bf16x8, ap1u);
            // PV
            bf16x8 vb00 = *(const bf16x8*)&vp[voff];
            bf16x8 vb01 = *(const bf16x8*)&vp[voff + 32];
            bf16x8 vb10 = *(const bf16x8*)&vp[1152 + voff];
            bf16x8 vb11 = *(const bf16x8*)&vp[1152 + voff + 32];
            __builtin_amdgcn_s_setprio(1);
            acc0 = MFMA_(ap0, vb00, acc0, 0, 0, 0);
            acc0 = MFMA_(ap1, vb01, acc0, 0, 0, 0);
            acc1 = MFMA_(ap0, vb10, acc1, 0, 0, 0);
            acc1 = MFMA_(ap1, vb11, acc1, 0, 0, 0);
            __builtin_amdgcn_s_setprio(0);
        }
    }

    // ---- epilogue: ctx -> Cb bf16 (s_ctx aliases buffers; barrier both) ---
    __syncthreads();
#pragma unroll
    for (int reg = 0; reg < 4; ++reg) {
        int row = w * 16 + g * 4 + reg;
        s_ctx[row * 28 + n16] = acc0[reg];
        if (n16 < 8) s_ctx[row * 28 + 16 + n16] = acc1[reg];
    }
    __syncthreads();
    if (t < 384) {
        int r = t / 3, c = t % 3;             // 3 x uint4 (8 bf16) per row
        const float* src = &s_ctx[r * 28 + c * 8];
        uint4 u;
        u.x = pack2(src[0], src[1]); u.y = pack2(src[2], src[3]);
        u.z = pack2(src[4], src[5]); u.w = pack2(src[6], src[7]);
        *(uint4*)&Cb[(size_t)(b * S_ + row0 + r) * 160 + h * 24 + c * 8] = u;
    }
}

// ---------------------------------------------------------------------------
// outln: out = LN(ctx @ Wl^T + lb + residual) * g + beta.
// ctx comes in as bf16 Cb[16384][160] -> pure uint4 LDS staging.
// Block = 1024 threads (16 waves) on 64 rows -> 16 waves/CU (was 8).
// Waves: 4 row-groups (wq) x 4 j-groups (jg covering {3,2,2,2} d-tiles).
// ---------------------------------------------------------------------------
__global__ __launch_bounds__(1024)
void outln_kernel(const float* __restrict__ Qres, const ushort* __restrict__ Wlp,
                  const ushort* __restrict__ Cb,
                  const float* __restrict__ lg, const float* __restrict__ lbeta,
                  float* __restrict__ io) {
    __shared__ __attribute__((aligned(16))) ushort s_a[64 * 168];
    __shared__ __attribute__((aligned(16))) ushort s_w[144 * 168];
    __shared__ float s_red[4][2][64];
    const int t = threadIdx.x;                // 0..1023
    const int w = t >> 6, n16 = t & 15, g = (t >> 4) & 3;
    const int wq = w & 3, jg = w >> 2;        // row-group, j-group
    const int nt_base = (jg == 0) ? 0 : (1 + 2 * jg);   // {0,3,5,7}
    const int nt_cnt  = (jg == 0) ? 3 : 2;
    const int row0 = blockIdx.x * 64;

    const ushort* Cr = Cb + (size_t)row0 * 160;
    for (int idx = t; idx < 1152; idx += 1024) {    // cols 0..143 only
        int r = idx / 18, c8 = (idx % 18) * 8;
        *(uint4*)&s_a[r * 168 + c8] = *(const uint4*)&Cr[r * 160 + c8];
    }
    if (t < 64) {
        uint4 pad = {0x00003F80u, 0u, 0u, 0u};
        uint4 z4  = {0u, 0u, 0u, 0u};
        *(uint4*)&s_a[t * 168 + 144] = pad;
        *(uint4*)&s_a[t * 168 + 152] = z4;
    }
    for (int idx = t; idx < 2880; idx += 1024) {
        int r = idx / 20, c8 = (idx % 20) * 8;
        *(uint4*)&s_w[r * 168 + c8] = *(const uint4*)&Wlp[r * 160 + c8];
    }
    __syncthreads();

    f32x4 acc[3];
#pragma unroll
    for (int j = 0; j < 3; ++j) acc[j] = (f32x4){0.f, 0.f, 0.f, 0.f};
#pragma unroll
    for (int ks = 0; ks < 5; ++ks) {
        bf16x8 av = *(const bf16x8*)&s_a[(wq * 16 + n16) * 168 + ks * 32 + g * 8];
        for (int j = 0; j < nt_cnt; ++j) {
            bf16x8 bv = *(const bf16x8*)&s_w[((nt_base + j) * 16 + n16) * 168 + ks * 32 + g * 8];
            acc[j] = MFMA_(av, bv, acc[j], 0, 0, 0);
        }
    }
    float vals[3][4], s1[4] = {0, 0, 0, 0}, s2[4] = {0, 0, 0, 0};
    for (int j = 0; j < nt_cnt; ++j) {
        int d = (nt_base + j) * 16 + n16;
#pragma unroll
        for (int reg = 0; reg < 4; ++reg) {
            int row = row0 + wq * 16 + g * 4 + reg;
            float v = acc[j][reg] + Qres[(size_t)row * DM_ + d];
            vals[j][reg] = v;
            s1[reg] += v; s2[reg] = fmaf(v, v, s2[reg]);
        }
    }
#pragma unroll
    for (int off = 1; off < 16; off <<= 1) {
#pragma unroll
        for (int reg = 0; reg < 4; ++reg) {
            s1[reg] += __shfl_xor(s1[reg], off);
            s2[reg] += __shfl_xor(s2[reg], off);
        }
    }
    if (n16 == 0) {
#pragma unroll
        for (int reg = 0; reg < 4; ++reg) {
            int rr = wq * 16 + g * 4 + reg;
            s_red[jg][0][rr] = s1[reg];
            s_red[jg][1][rr] = s2[reg];
        }
    }
    __syncthreads();
    float mu[4], rs[4];
#pragma unroll
    for (int reg = 0; reg < 4; ++reg) {
        int rr = wq * 16 + g * 4 + reg;
        float S1 = s_red[0][0][rr] + s_red[1][0][rr] + s_red[2][0][rr] + s_red[3][0][rr];
        float S2 = s_red[0][1][rr] + s_red[1][1][rr] + s_red[2][1][rr] + s_red[3][1][rr];
        float m = S1 * (1.f / 144.f);
        mu[reg] = m;
        rs[reg] = rsqrtf(S2 * (1.f / 144.f) - m * m + 1e-5f);
    }
    for (int j = 0; j < nt_cnt; ++j) {
        int d = (nt_base + j) * 16 + n16;
        float gv = lg[d], bv = lbeta[d];
#pragma unroll
        for (int reg = 0; reg < 4; ++reg) {
            int row = row0 + wq * 16 + g * 4 + reg;
            io[(size_t)row * DM_ + d] = (vals[j][reg] - mu[reg]) * rs[reg] * gv + bv;
        }
    }
}

// ---------------------------------------------------------------------------
extern "C" void kernel_launch(void* const* d_in, const int* in_sizes, int n_in,
                              void* d_out, int out_size, void* d_ws, size_t ws_size,
                              hipStream_t stream) {
    const float* Q     = (const float*)d_in[0];
    const float* K     = (const float*)d_in[1];
    const float* V     = (const float*)d_in[2];
    // d_in[3] = attn_mask: dead code in the reference, ignored.
    const float* Wq_w  = (const float*)d_in[4];
    const float* Wq_b  = (const float*)d_in[5];
    const float* lin_w = (const float*)d_in[6];
    const float* lin_b = (const float*)d_in[7];
    const float* ln_g  = (const float*)d_in[8];
    const float* ln_b  = (const float*)d_in[9];
    float* out = (float*)d_out;

    ushort* Ktt = (ushort*)d_ws;                            // 6,291,456 B
    ushort* Vtt = (ushort*)((char*)d_ws + 6291456);         // 6,291,456 B
    ushort* Whq = (ushort*)((char*)d_ws + 12582912);        // 61,440 B
    ushort* Wlp = (ushort*)((char*)d_ws + 12644352);        // 46,080 B
    ushort* Cb  = (ushort*)((char*)d_ws + 12690432);        // 5,242,880 B

    prep_kernel<<<1746, 256, 0, stream>>>(K, V, Wq_w, Wq_b, lin_w, lin_b,
                                          Ktt, Vtt, Whq, Wlp);
    attn_kernel<<<dim3(S_ / 128, H_, B_), 512, 0, stream>>>(Q, Whq, Ktt, Vtt, Cb);
    outln_kernel<<<(B_ * S_) / 64, 1024, 0, stream>>>(Q, Wlp, Cb, ln_g, ln_b, out);
}

// Round 6
// 252.992 us; speedup vs baseline: 1.0725x; 1.0009x over previous
//
#include <hip/hip_runtime.h>
#include <hip/hip_bf16.h>

#define B_  8
#define S_  2048
#define H_  6
#define DK_ 24
#define DM_ 144

// tanh(SCALE*c) ~= c*(K0 + K1*t + K2*t^2), t = c^2, SCALE = 0.1/sqrt(24).
#define TK0  2.0412414523193153e-02f
#define TK1 -2.8350575726379381e-06f
#define TK2  4.7250959543965635e-10f

typedef __bf16 bf16x8 __attribute__((ext_vector_type(8)));
typedef __bf16 bf16x2 __attribute__((ext_vector_type(2)));
typedef float  f32x4  __attribute__((ext_vector_type(4)));
typedef float  f32x2  __attribute__((ext_vector_type(2)));

#define MFMA_ __builtin_amdgcn_mfma_f32_16x16x32_bf16

__device__ __forceinline__ unsigned short f2bf(float f) {
    return __builtin_bit_cast(unsigned short, (__bf16)f);
}
__device__ __forceinline__ uint pack2(float a, float b) {
    bf16x2 v; v[0] = (__bf16)a; v[1] = (__bf16)b;
    return __builtin_bit_cast(uint, v);
}
// packed tanh on a pair -> packed bf16 word (v_pk_mul_f32 / v_pk_fma_f32).
__device__ __forceinline__ uint tanh2_pack(float a, float b) {
    f32x2 c; c[0] = a; c[1] = b;
    f32x2 t = c * c;
    f32x2 u = t * TK2 + TK1;
    u = t * u + TK0;
    f32x2 r = c * u;
    return pack2(r[0], r[1]);
}
// pack 8 f32 (2 float4) -> uint4 of 8 bf16
__device__ __forceinline__ uint4 pack8(const float4& fa, const float4& fb) {
    uint4 u;
    u.x = pack2(fa.x, fa.y); u.y = pack2(fa.z, fa.w);
    u.z = pack2(fb.x, fb.y); u.w = pack2(fb.z, fb.w);
    return u;
}

// lane-bit-5 swap: x' <- lower-32-half data of {x,y}; y' <- upper-half data.
__device__ __forceinline__ void swap32(uint &x, uint &y) {
    auto r = __builtin_amdgcn_permlane32_swap(x, y, false, false);
    x = r[0]; y = r[1];
}
// lane-bit-4 swap: x' <- bit4==0 data of {x,y}; y' <- bit4==1 data.
__device__ __forceinline__ void swap16(uint &x, uint &y, bool hi16) {
#if __has_builtin(__builtin_amdgcn_permlane16_swap)
    (void)hi16;
    auto r = __builtin_amdgcn_permlane16_swap(x, y, false, false);
    x = r[0]; y = r[1];
#else
    uint xs = __builtin_amdgcn_ds_swizzle(x, 0x401F);   // lane ^ 16
    uint ys = __builtin_amdgcn_ds_swizzle(y, 0x401F);
    uint nx = hi16 ? ys : x;
    uint ny = hi16 ? y : xs;
    x = nx; y = ny;
#endif
}

// ---------------------------------------------------------------------------
// prep_v: V f32 -> Vtt[bh][kt][32 d][64 s] bf16 (rows 24..31 zero).
// (K and weights are now converted inline in attn/outln -- no round trip.)
// ---------------------------------------------------------------------------
__global__ __launch_bounds__(256)
void prep_v_kernel(const float* __restrict__ V, ushort* __restrict__ Vtt) {
    __shared__ float sv[64 * 25];
    const int t = threadIdx.x;
    const int bid = blockIdx.x;
    const int kt = bid & 31, bh = bid >> 5;
    const size_t tile = (size_t)(bh * 32 + kt);
    const float4* Vs = (const float4*)(V + ((size_t)bh * S_ + kt * 64) * DK_);
    for (int idx = t; idx < 384; idx += 256) {
        int r = idx / 6, c4 = (idx % 6) * 4;
        *(float4*)&sv[r * 25 + c4] = Vs[idx];
    }
    __syncthreads();
    int d = t >> 3, s8 = (t & 7) * 8;
    uint4 o = {0u,0u,0u,0u};
    if (d < DK_) {
        o.x = pack2(sv[(s8 + 0) * 25 + d], sv[(s8 + 1) * 25 + d]);
        o.y = pack2(sv[(s8 + 2) * 25 + d], sv[(s8 + 3) * 25 + d]);
        o.z = pack2(sv[(s8 + 4) * 25 + d], sv[(s8 + 5) * 25 + d]);
        o.w = pack2(sv[(s8 + 6) * 25 + d], sv[(s8 + 7) * 25 + d]);
    }
    ((uint4*)Vtt)[tile * 256 + t] = o;
}

// ---------------------------------------------------------------------------
// attn: fused qproj + tanh-attention.  (R2 geometry: 16 rows/wave.)
// Block = 512 threads (8 waves) = 128 q-rows of one (b,h); wave owns 16 rows.
// Grid 768 = 3 blocks/CU, LDS 38KB (s_q/s_ctx alias the chunk buffers),
// 24 waves/CU.
// K staged DIRECTLY from f32 K (coalesced 2xfloat4, packed at ds_write time);
// Wq/Wqb consumed directly as f32 in Phase A (no weight prep).
// K/V staged in 2-TILE CHUNKS, double-buffered -> ONE barrier per 2 k-tiles.
// P never touches LDS: QK^T frag -> PV A-frag via permlane32/16 butterfly.
// Output: bf16 ctx tile into Cb[16384][160] (outln-staging layout).
// ---------------------------------------------------------------------------
__global__ __launch_bounds__(512, 6)
void attn_kernel(const float* __restrict__ Q, const float* __restrict__ K,
                 const float* __restrict__ Wq, const float* __restrict__ Wqb,
                 const ushort* __restrict__ Vtt, ushort* __restrict__ Cb) {
    __shared__ __attribute__((aligned(16))) char smem[38912];
    ushort* s_k  = (ushort*)smem;             // 2 chunks x 2 x 2560 us [0,20480)B
    ushort* s_vt = (ushort*)(smem + 20480);   // 2 chunks x 2 x 2304 us [20480,38912)B
    ushort* s_q  = (ushort*)smem;             // phase-A alias: 128 x 40 (10240B)
    float*  s_ctx = (float*)smem;             // epilogue alias: 128 x 28 f32

    const int t = threadIdx.x;
    const int w = t >> 6, n16 = t & 15, g = (t >> 4) & 3;
    const bool hi16 = (t & 16) != 0;
    const int qp = blockIdx.x, h = blockIdx.y, b = blockIdx.z;
    const int bh = b * H_ + h;
    const int row0 = qp * 128;

    const uint4* Vb4 = (const uint4*)Vtt + (size_t)bh * 8192;   // 32 tiles x 256
    const float* Kf  = K + (size_t)bh * S_ * DK_;               // [2048][24] f32

    // staging role: waves 0-3 -> K (t<256), waves 4-7 -> V
    const int t2 = t & 255;
    const bool isK = (t < 256);
    const int krow = t2 >> 2, kcq = t2 & 3;           // K: row, col-quad
    const bool kreal = isK && (kcq < 3);              // kcq==3 -> pad zeros
    const int stoff = isK ? (krow * 40 + kcq * 8)
                          : ((t2 >> 3) * 72 + (t2 & 7) * 8);
    // staging registers: K waves hold f32 (packed at write), V waves bf16.
    float4 kf0a, kf0b, kf1a, kf1b;
    uint4 sv0, sv1;
    if (isK) {
        if (kreal) {
            const float* p0 = &Kf[(size_t)krow * DK_ + kcq * 8];
            kf0a = *(const float4*)p0; kf0b = *(const float4*)(p0 + 4);
            const float* p1 = &Kf[(size_t)(64 + krow) * DK_ + kcq * 8];
            kf1a = *(const float4*)p1; kf1b = *(const float4*)(p1 + 4);
        }
    } else {
        sv0 = Vb4[t2]; sv1 = Vb4[256 + t2];
    }

    // ---- Phase A: q = Q @ Wq^T + bias (k=144 col), weights from f32 ------
    const f32x4 zf = {0.f, 0.f, 0.f, 0.f};
    {
        const float* Qr = Q + (size_t)(b * S_ + row0 + w * 16 + n16) * DM_;
        const float* Wqh  = Wq + (size_t)h * DK_ * DM_;   // 24 x 144
        const float* Wqbh = Wqb + h * DK_;
        f32x4 qa0 = zf, qa1 = zf;
#pragma unroll
        for (int ks = 0; ks < 5; ++ks) {
            bf16x8 av;
            if (ks < 4 || g < 2) {            // real cols (ks=4,g<2 -> 128..143)
                float4 f0 = *(const float4*)&Qr[ks * 32 + g * 8];
                float4 f1 = *(const float4*)&Qr[ks * 32 + g * 8 + 4];
                av = __builtin_bit_cast(bf16x8, pack8(f0, f1));
            } else {                          // k=144 bias col (g==2), zeros (g==3)
                uint4 u = {0u, 0u, 0u, 0u};
                if (g == 2) u.x = 0x00003F80u;
                av = __builtin_bit_cast(bf16x8, u);
            }
            bf16x8 bv0, bv1;
            {   // B-frag row d=n16 (always real)
                uint4 u = {0u, 0u, 0u, 0u};
                if (ks < 4 || g < 2) {
                    const float* p = &Wqh[n16 * DM_ + ks * 32 + g * 8];
                    u = pack8(*(const float4*)p, *(const float4*)(p + 4));
                } else if (g == 2) {
                    u.x = pack2(Wqbh[n16], 0.f);
                }
                bv0 = __builtin_bit_cast(bf16x8, u);
            }
            {   // B-frag row d=16+n16 (real only for n16<8)
                uint4 u = {0u, 0u, 0u, 0u};
                if (n16 < 8) {
                    int d = 16 + n16;
                    if (ks < 4 || g < 2) {
                        const float* p = &Wqh[d * DM_ + ks * 32 + g * 8];
                        u = pack8(*(const float4*)p, *(const float4*)(p + 4));
                    } else if (g == 2) {
                        u.x = pack2(Wqbh[d], 0.f);
                    }
                }
                bv1 = __builtin_bit_cast(bf16x8, u);
            }
            qa0 = MFMA_(av, bv0, qa0, 0, 0, 0);
            qa1 = MFMA_(av, bv1, qa1, 0, 0, 0);
        }
#pragma unroll
        for (int reg = 0; reg < 4; ++reg) {   // wave-local transpose (no barrier)
            int r = (w * 16 + g * 4 + reg) * 40;
            s_q[r + n16]      = f2bf(qa0[reg]);
            s_q[r + 16 + n16] = f2bf(qa1[reg]);   // d 24..31 zero rows
        }
    }
    const bf16x8 qf = *(const bf16x8*)&s_q[(w * 16 + n16) * 40 + g * 8];
    __syncthreads();   // s_q aliases K chunk buffers: protect before staging

    // ---- k-loop: 16 chunks of 2 tiles, double-buffered, 1 barrier/chunk --
    const int aoff = n16 * 40 + g * 8;        // hoisted LDS read offsets
    const int voff = n16 * 72 + g * 8;
    f32x4 acc0 = zf, acc1 = zf;

    for (int c = 0; c < 16; ++c) {
        ushort* kc = s_k + (c & 1) * 5120;
        ushort* vc = s_vt + (c & 1) * 4608;
        if (isK) {
            uint4 u0 = {0u,0u,0u,0u}, u1 = {0u,0u,0u,0u};
            if (kreal) { u0 = pack8(kf0a, kf0b); u1 = pack8(kf1a, kf1b); }
            *(uint4*)&kc[stoff] = u0;
            *(uint4*)&kc[2560 + stoff] = u1;
        } else {
            *(uint4*)&vc[stoff] = sv0;
            *(uint4*)&vc[2304 + stoff] = sv1;
        }
        __syncthreads();
        {   // prefetch next chunk AFTER the barrier
            int nt = (2 * c + 2) & 31;
            if (isK) {
                if (kreal) {
                    const float* p0 = &Kf[(size_t)(nt * 64 + krow) * DK_ + kcq * 8];
                    kf0a = *(const float4*)p0; kf0b = *(const float4*)(p0 + 4);
                    const float* p1 = &Kf[(size_t)((nt + 1) * 64 + krow) * DK_ + kcq * 8];
                    kf1a = *(const float4*)p1; kf1b = *(const float4*)(p1 + 4);
                }
            } else {
                sv0 = Vb4[nt * 256 + t2];
                sv1 = Vb4[nt * 256 + 256 + t2];
            }
        }
#pragma unroll
        for (int p = 0; p < 2; ++p) {
            const ushort* kp = kc + p * 2560;
            const ushort* vp = vc + p * 2304;
            // S strips -> P in registers
            bf16x8 a0 = *(const bf16x8*)&kp[aoff];
            bf16x8 a1 = *(const bf16x8*)&kp[640 + aoff];
            bf16x8 a2 = *(const bf16x8*)&kp[1280 + aoff];
            bf16x8 a3 = *(const bf16x8*)&kp[1920 + aoff];
            __builtin_amdgcn_s_setprio(1);
            f32x4 c0 = MFMA_(a0, qf, zf, 0, 0, 0);
            f32x4 c1 = MFMA_(a1, qf, zf, 0, 0, 0);
            f32x4 c2 = MFMA_(a2, qf, zf, 0, 0, 0);
            f32x4 c3 = MFMA_(a3, qf, zf, 0, 0, 0);
            __builtin_amdgcn_s_setprio(0);
            // tanh -> packed bf16 words: W[strip][pair], lane holds
            // P[q=n16][s = strip*16 + g*4 + 2*pair + {0,1}]
            uint W0p0 = tanh2_pack(c0[0], c0[1]);
            uint W0p1 = tanh2_pack(c0[2], c0[3]);
            uint W1p0 = tanh2_pack(c1[0], c1[1]);
            uint W1p1 = tanh2_pack(c1[2], c1[3]);
            uint W2p0 = tanh2_pack(c2[0], c2[1]);
            uint W2p1 = tanh2_pack(c2[2], c2[3]);
            uint W3p0 = tanh2_pack(c3[0], c3[1]);
            uint W3p1 = tanh2_pack(c3[2], c3[3]);
            // butterfly: bit5 then bit4 -> PV A-frags in-register.
            // ap0 lane g = P[q=n16][s=g*8+0..7], ap1 = s=32+g*8+0..7.
            swap32(W0p0, W1p0);
            swap32(W2p0, W3p0);
            swap32(W0p1, W1p1);
            swap32(W2p1, W3p1);
            swap16(W0p0, W1p0, hi16);
            swap16(W2p0, W3p0, hi16);
            swap16(W0p1, W1p1, hi16);
            swap16(W2p1, W3p1, hi16);
            uint4 ap0u, ap1u;
            ap0u.x = W0p0; ap0u.y = W0p1; ap0u.z = W1p0; ap0u.w = W1p1;
            ap1u.x = W2p0; ap1u.y = W2p1; ap1u.z = W3p0; ap1u.w = W3p1;
            bf16x8 ap0 = __builtin_bit_cast(bf16x8, ap0u);
            bf16x8 ap1 = __builtin_bit_cast(bf16x8, ap1u);
            // PV
            bf16x8 vb00 = *(const bf16x8*)&vp[voff];
            bf16x8 vb01 = *(const bf16x8*)&vp[voff + 32];
            bf16x8 vb10 = *(const bf16x8*)&vp[1152 + voff];
            bf16x8 vb11 = *(const bf16x8*)&vp[1152 + voff + 32];
            __builtin_amdgcn_s_setprio(1);
            acc0 = MFMA_(ap0, vb00, acc0, 0, 0, 0);
            acc0 = MFMA_(ap1, vb01, acc0, 0, 0, 0);
            acc1 = MFMA_(ap0, vb10, acc1, 0, 0, 0);
            acc1 = MFMA_(ap1, vb11, acc1, 0, 0, 0);
            __builtin_amdgcn_s_setprio(0);
        }
    }

    // ---- epilogue: ctx -> Cb bf16 (s_ctx aliases buffers; barrier both) ---
    __syncthreads();
#pragma unroll
    for (int reg = 0; reg < 4; ++reg) {
        int row = w * 16 + g * 4 + reg;
        s_ctx[row * 28 + n16] = acc0[reg];
        if (n16 < 8) s_ctx[row * 28 + 16 + n16] = acc1[reg];
    }
    __syncthreads();
    if (t < 384) {
        int r = t / 3, c = t % 3;             // 3 x uint4 (8 bf16) per row
        const float* src = &s_ctx[r * 28 + c * 8];
        uint4 u;
        u.x = pack2(src[0], src[1]); u.y = pack2(src[2], src[3]);
        u.z = pack2(src[4], src[5]); u.w = pack2(src[6], src[7]);
        *(uint4*)&Cb[(size_t)(b * S_ + row0 + r) * 160 + h * 24 + c * 8] = u;
    }
}

// ---------------------------------------------------------------------------
// outln: out = LN(ctx @ Wl^T + lb + residual) * g + beta.
// ctx comes in as bf16 Cb[16384][160]; lin_w/lin_b consumed directly as f32
// (converted during LDS staging -- no weight prep).
// Block = 1024 threads (16 waves) on 64 rows -> 16 waves/CU.
// Waves: 4 row-groups (wq) x 4 j-groups (jg covering {3,2,2,2} d-tiles).
// ---------------------------------------------------------------------------
__global__ __launch_bounds__(1024)
void outln_kernel(const float* __restrict__ Qres, const float* __restrict__ Wl,
                  const float* __restrict__ lb, const ushort* __restrict__ Cb,
                  const float* __restrict__ lg, const float* __restrict__ lbeta,
                  float* __restrict__ io) {
    __shared__ __attribute__((aligned(16))) ushort s_a[64 * 168];
    __shared__ __attribute__((aligned(16))) ushort s_w[144 * 168];
    __shared__ float s_red[4][2][64];
    const int t = threadIdx.x;                // 0..1023
    const int w = t >> 6, n16 = t & 15, g = (t >> 4) & 3;
    const int wq = w & 3, jg = w >> 2;        // row-group, j-group
    const int nt_base = (jg == 0) ? 0 : (1 + 2 * jg);   // {0,3,5,7}
    const int nt_cnt  = (jg == 0) ? 3 : 2;
    const int row0 = blockIdx.x * 64;

    const ushort* Cr = Cb + (size_t)row0 * 160;
    for (int idx = t; idx < 1152; idx += 1024) {    // cols 0..143 only
        int r = idx / 18, c8 = (idx % 18) * 8;
        *(uint4*)&s_a[r * 168 + c8] = *(const uint4*)&Cr[r * 160 + c8];
    }
    if (t < 64) {
        uint4 pad = {0x00003F80u, 0u, 0u, 0u};
        uint4 z4  = {0u, 0u, 0u, 0u};
        *(uint4*)&s_a[t * 168 + 144] = pad;
        *(uint4*)&s_a[t * 168 + 152] = z4;
    }
    for (int idx = t; idx < 2880; idx += 1024) {    // lin_w f32 -> bf16 inline
        int r = idx / 20, c8 = (idx % 20) * 8;
        uint4 u = {0u, 0u, 0u, 0u};
        if (c8 < DM_) {
            const float* p = &Wl[r * DM_ + c8];
            u = pack8(*(const float4*)p, *(const float4*)(p + 4));
        } else if (c8 == DM_) {
            u.x = pack2(lb[r], 0.f);
        }
        *(uint4*)&s_w[r * 168 + c8] = u;
    }
    __syncthreads();

    f32x4 acc[3];
#pragma unroll
    for (int j = 0; j < 3; ++j) acc[j] = (f32x4){0.f, 0.f, 0.f, 0.f};
#pragma unroll
    for (int ks = 0; ks < 5; ++ks) {
        bf16x8 av = *(const bf16x8*)&s_a[(wq * 16 + n16) * 168 + ks * 32 + g * 8];
        for (int j = 0; j < nt_cnt; ++j) {
            bf16x8 bv = *(const bf16x8*)&s_w[((nt_base + j) * 16 + n16) * 168 + ks * 32 + g * 8];
            acc[j] = MFMA_(av, bv, acc[j], 0, 0, 0);
        }
    }
    float vals[3][4], s1[4] = {0, 0, 0, 0}, s2[4] = {0, 0, 0, 0};
    for (int j = 0; j < nt_cnt; ++j) {
        int d = (nt_base + j) * 16 + n16;
#pragma unroll
        for (int reg = 0; reg < 4; ++reg) {
            int row = row0 + wq * 16 + g * 4 + reg;
            float v = acc[j][reg] + Qres[(size_t)row * DM_ + d];
            vals[j][reg] = v;
            s1[reg] += v; s2[reg] = fmaf(v, v, s2[reg]);
        }
    }
#pragma unroll
    for (int off = 1; off < 16; off <<= 1) {
#pragma unroll
        for (int reg = 0; reg < 4; ++reg) {
            s1[reg] += __shfl_xor(s1[reg], off);
            s2[reg] += __shfl_xor(s2[reg], off);
        }
    }
    if (n16 == 0) {
#pragma unroll
        for (int reg = 0; reg < 4; ++reg) {
            int rr = wq * 16 + g * 4 + reg;
            s_red[jg][0][rr] = s1[reg];
            s_red[jg][1][rr] = s2[reg];
        }
    }
    __syncthreads();
    float mu[4], rs[4];
#pragma unroll
    for (int reg = 0; reg < 4; ++reg) {
        int rr = wq * 16 + g * 4 + reg;
        float S1 = s_red[0][0][rr] + s_red[1][0][rr] + s_red[2][0][rr] + s_red[3][0][rr];
        float S2 = s_red[0][1][rr] + s_red[1][1][rr] + s_red[2][1][rr] + s_red[3][1][rr];
        float m = S1 * (1.f / 144.f);
        mu[reg] = m;
        rs[reg] = rsqrtf(S2 * (1.f / 144.f) - m * m + 1e-5f);
    }
    for (int j = 0; j < nt_cnt; ++j) {
        int d = (nt_base + j) * 16 + n16;
        float gv = lg[d], bv = lbeta[d];
#pragma unroll
        for (int reg = 0; reg < 4; ++reg) {
            int row = row0 + wq * 16 + g * 4 + reg;
            io[(size_t)row * DM_ + d] = (vals[j][reg] - mu[reg]) * rs[reg] * gv + bv;
        }
    }
}

// ---------------------------------------------------------------------------
extern "C" void kernel_launch(void* const* d_in, const int* in_sizes, int n_in,
                              void* d_out, int out_size, void* d_ws, size_t ws_size,
                              hipStream_t stream) {
    const float* Q     = (const float*)d_in[0];
    const float* K     = (const float*)d_in[1];
    const float* V     = (const float*)d_in[2];
    // d_in[3] = attn_mask: dead code in the reference, ignored.
    const float* Wq_w  = (const float*)d_in[4];
    const float* Wq_b  = (const float*)d_in[5];
    const float* lin_w = (const float*)d_in[6];
    const float* lin_b = (const float*)d_in[7];
    const float* ln_g  = (const float*)d_in[8];
    const float* ln_b  = (const float*)d_in[9];
    float* out = (float*)d_out;

    ushort* Vtt = (ushort*)d_ws;                            // 6,291,456 B
    ushort* Cb  = (ushort*)((char*)d_ws + 6291456);         // 5,242,880 B

    prep_v_kernel<<<1536, 256, 0, stream>>>(V, Vtt);
    attn_kernel<<<dim3(S_ / 128, H_, B_), 512, 0, stream>>>(Q, K, Wq_w, Wq_b, Vtt, Cb);
    outln_kernel<<<(B_ * S_) / 64, 1024, 0, stream>>>(Q, lin_w, lin_b, Cb, ln_g, ln_b, out);
}